// Round 5
// baseline (232.849 us; speedup 1.0000x reference)
//
#include <hip/hip_runtime.h>
#include <math.h>

#define BB 32
#define TS 8192
#define DSEG 32
#define SS 256
#define DM 256
#define W 512
#define SPLIT 8
#define CAND (W / SPLIT)   // 64 candidates per search block
#define CAP 2048           // max segments per bucket (empirical max <= 1024)

// ---------------------------------------------------------------------------
// Kernel A: fused prep (blocks 0..1023) + per-batch Haar (1024..1055)
//           + pos-emb table (1056..1311).
// prep arithmetic bit-identical to the passing R3 kernel; adds bucket-list
// scatter (order-independent consumer).
// ---------------------------------------------------------------------------
__global__ __launch_bounds__(256) void prep_haar_pe_kernel(
    const float* __restrict__ x,
    float* __restrict__ segn_g,                 // [8192][32]
    unsigned char* __restrict__ bucketc,        // [8192]
    unsigned long long* __restrict__ bestkey,   // [8192]
    float* __restrict__ hout,                   // [32][64]
    float* __restrict__ pe_g,                   // [256][256]
    int* __restrict__ bucket_cnt,               // [256] (pre-zeroed)
    int* __restrict__ list_g)                   // [256][CAP]
{
    const int blk = blockIdx.x;
    const int t = threadIdx.x;

    if (blk < 1024) {
        // ---------------- prep: 8 segments per block ----------------
        const int segBase = blk * 8;
        __shared__ float sseg[8][32];
        sseg[t >> 5][t & 31] = x[(size_t)segBase * 32 + t];
        __syncthreads();

        const int hw = t >> 5;        // segment slot 0..7
        const int h = hw & 1;         // half within this wave
        const int l = t & 31;
        const int seg = segBase + hw;

        float v = sseg[hw][l];
        float mn = v, mx = v, sm = v;
#pragma unroll
        for (int m = 1; m <= 16; m <<= 1) {
            mn = fminf(mn, __shfl_xor(mn, m));
            mx = fmaxf(mx, __shfl_xor(mx, m));
            sm += __shfl_xor(sm, m);
        }
        float mean = sm * (1.0f / 32.0f);
        float cm = 0.0f;
        if (l < 8) {
            cm = ((sseg[hw][4 * l] + sseg[hw][4 * l + 1]) + sseg[hw][4 * l + 2]) +
                 sseg[hw][4 * l + 3];
            cm *= 0.25f;
        }
        unsigned long long bal = __ballot(l < 8 && cm > mean);
        segn_g[(size_t)seg * 32 + l] = (v - mn) / (mx - mn + 1e-8f);
        if (l == 0) {
            int bucket = (int)((bal >> (h * 32)) & 0xFF);
            bucketc[seg] = (unsigned char)bucket;
            int slot = atomicAdd(bucket_cnt + bucket, 1);
            if (slot < CAP) list_g[bucket * CAP + slot] = seg;
        }
        if (l == 1) bestkey[seg] = ~0ULL;
    } else if (blk < 1056) {
        // ---------------- haar: one wave per batch ----------------
        const int b = blk - 1024;
        const int lane = t;
        if (lane >= 64) return;
        const float* xb = x + (size_t)b * TS + (size_t)lane * 128;
        const float is2 = 0.70710678118654752440f;

        float a[64];  // first reduction level folded into the load
#pragma unroll
        for (int i = 0; i < 32; ++i) {
            float4 u = *(const float4*)(xb + 4 * i);
            a[2 * i + 0] = (u.x + u.y) * is2;
            a[2 * i + 1] = (u.z + u.w) * is2;
        }
#pragma unroll
        for (int len = 64; len > 1; len >>= 1) {
#pragma unroll
            for (int j = 0; j < (len >> 1); ++j)
                a[j] = (a[2 * j] + a[2 * j + 1]) * is2;
        }
        float val = a[0];  // a7[lane]
        float* ob = hout + b * 64;
#pragma unroll
        for (int len = 64; len > 1; len >>= 1) {
            float e = __shfl(val, 2 * lane);
            float o = __shfl(val, 2 * lane + 1);
            int half = len >> 1;
            if (lane < half) {
                ob[half + lane] = (e - o) * is2;
                val = (e + o) * is2;
            }
        }
        if (lane == 0) ob[0] = val;
    } else {
        // ---------------- pos-emb table: one block per s ----------------
        const int s = blk - 1056;
        const float cexp = -9.210340371976184f / 256.0f;  // -ln(10000)/256
        float dv = expf((float)(t & ~1) * cexp);
        float ang = (float)s * dv;
        pe_g[s * DM + t] = (t & 1) ? cosf(ang) : sinf(ang);
    }
}

// ---------------------------------------------------------------------------
// Kernel B: VQ search. Block = (bucket, part): 64 candidates staged in LDS
// (XOR-swizzled), all bucket members iterated 2-per-wave. Lane = candidate.
// Distance order d=0..31 bit-identical; global atomicMin on (dist<<32)|w
// reproduces exact first-min tie-break across parts.
// ---------------------------------------------------------------------------
__global__ __launch_bounds__(512) void search_kernel(
    const float* __restrict__ vocab,            // [256][512][32]
    const float* __restrict__ segn_g,
    const int* __restrict__ bucket_cnt,
    const int* __restrict__ list_g,
    unsigned long long* __restrict__ bestkey)
{
    const int bucket = blockIdx.x >> 3;
    const int part = blockIdx.x & 7;
    const int t = threadIdx.x;
    const int lane = t & 63;
    const int wid = t >> 6;

    __shared__ float vsh[CAND * 32];   // 8 KB, swizzled

    // stage 64 candidate rows: 512 float4s, one per thread
    {
        const float* vb =
            vocab + ((size_t)bucket * W + (size_t)part * CAND) * DSEG;
        int r = t >> 3, q = t & 7;
        float4 u = ((const float4*)vb)[t];
        int sq = q ^ (r & 7);
        *(float4*)&vsh[r * 32 + sq * 4] = u;
    }
    int n = bucket_cnt[bucket];
    if (n > CAP) n = CAP;
    __syncthreads();
    if (n == 0) return;

    const int* lst = list_g + bucket * CAP;
    const unsigned wbase = (unsigned)(part * CAND);

    for (int i = 2 * wid; i < n; i += 16) {
        const int segA = lst[i];
        const bool hasB = (i + 1 < n);
        const int segB = hasB ? lst[i + 1] : segA;
        const float* spA = segn_g + (size_t)segA * 32;
        const float* spB = segn_g + (size_t)segB * 32;
        float svA[32], svB[32];
#pragma unroll
        for (int d = 0; d < 32; ++d) { svA[d] = spA[d]; svB[d] = spB[d]; }

        const int r = lane;
        float dA = 0.0f, dB = 0.0f;
#pragma unroll
        for (int q = 0; q < 8; ++q) {
            float4 u = *(const float4*)&vsh[r * 32 + ((q ^ (r & 7)) * 4)];
            dA += fabsf(u.x - svA[4 * q + 0]);
            dA += fabsf(u.y - svA[4 * q + 1]);
            dA += fabsf(u.z - svA[4 * q + 2]);
            dA += fabsf(u.w - svA[4 * q + 3]);
            dB += fabsf(u.x - svB[4 * q + 0]);
            dB += fabsf(u.y - svB[4 * q + 1]);
            dB += fabsf(u.z - svB[4 * q + 2]);
            dB += fabsf(u.w - svB[4 * q + 3]);
        }
        unsigned long long bestA =
            ((unsigned long long)__float_as_uint(dA) << 32) | (wbase + lane);
        unsigned long long bestB =
            ((unsigned long long)__float_as_uint(dB) << 32) | (wbase + lane);
#pragma unroll
        for (int m = 1; m < 64; m <<= 1) {
            unsigned long long oA = __shfl_xor(bestA, m);
            unsigned long long oB = __shfl_xor(bestB, m);
            if (oA < bestA) bestA = oA;
            if (oB < bestB) bestB = oB;
        }
        if (lane == 0) {
            atomicMin(bestkey + segA, bestA);
            if (hasB) atomicMin(bestkey + segB, bestB);
        }
    }
}

// ---------------------------------------------------------------------------
// Kernel C: gather + haar matvec + pe-table add + 2x LayerNorm.
// One WAVE per (b,s); lane l owns dims 4l..4l+3. No LDS, no syncthreads.
// ---------------------------------------------------------------------------
__global__ __launch_bounds__(256) void out_kernel(
    const float* __restrict__ wemb,     // [131072][256]
    const float* __restrict__ hemb,     // [7][256]
    const float* __restrict__ hcoef,    // [32][64]
    const float* __restrict__ pe_g,     // [256][256]
    const unsigned char* __restrict__ bucketc,
    const unsigned long long* __restrict__ bestkey,
    float* __restrict__ out)
{
    const int bs = (blockIdx.x << 2) + (threadIdx.x >> 6);  // segment id
    const int lane = threadIdx.x & 63;
    const int b = bs >> 8;
    const int s = bs & 255;

    const int bucket = bucketc[bs];
    const int bestw = (int)(unsigned)(bestkey[bs] & 0xFFFFFFFFull);

    // haar coefficients for this (b,s): 7 scalars (broadcast across wave)
    const float* hb = hcoef + b * 64;
    float hk[7];
    hk[0] = hb[0];
#pragma unroll
    for (int k = 1; k <= 6; ++k)
        hk[k] = hb[(1 << (k - 1)) + (s >> (8 - (k - 1)))];

    // haar matvec for 4 dims
    float h0 = 0.f, h1 = 0.f, h2 = 0.f, h3 = 0.f;
#pragma unroll
    for (int k = 0; k < 7; ++k) {
        float4 he = ((const float4*)(hemb + k * DM))[lane];
        h0 += hk[k] * he.x; h1 += hk[k] * he.y;
        h2 += hk[k] * he.z; h3 += hk[k] * he.w;
    }

    // LayerNorm(haar_embed) — wave tree reduction
    float sm = ((h0 + h1) + h2) + h3;
    float sq = ((h0 * h0 + h1 * h1) + h2 * h2) + h3 * h3;
#pragma unroll
    for (int m = 1; m < 64; m <<= 1) {
        sm += __shfl_xor(sm, m);
        sq += __shfl_xor(sq, m);
    }
    float mh = sm * (1.0f / 256.0f);
    float vh = fmaxf(sq * (1.0f / 256.0f) - mh * mh, 0.0f);
    float rs = 1.0f / sqrtf(vh + 1e-5f);
    float n0 = (h0 - mh) * rs, n1 = (h1 - mh) * rs;
    float n2 = (h2 - mh) * rs, n3 = (h3 - mh) * rs;

    // word embedding gather (coalesced float4 row read)
    const size_t row = (size_t)bucket * W + (size_t)bestw;
    float4 wv = ((const float4*)(wemb + row * DM))[lane];

    // positional embedding from table
    float4 pv = ((const float4*)(pe_g + s * DM))[lane];

    float o0 = wv.x + n0 + pv.x;
    float o1 = wv.y + n1 + pv.y;
    float o2 = wv.z + n2 + pv.z;
    float o3 = wv.w + n3 + pv.w;

    // final LayerNorm
    float sm2 = ((o0 + o1) + o2) + o3;
    float sq2 = ((o0 * o0 + o1 * o1) + o2 * o2) + o3 * o3;
#pragma unroll
    for (int m = 1; m < 64; m <<= 1) {
        sm2 += __shfl_xor(sm2, m);
        sq2 += __shfl_xor(sq2, m);
    }
    float mo = sm2 * (1.0f / 256.0f);
    float vo = fmaxf(sq2 * (1.0f / 256.0f) - mo * mo, 0.0f);
    float rs2 = 1.0f / sqrtf(vo + 1e-5f);

    float4 res;
    res.x = (o0 - mo) * rs2; res.y = (o1 - mo) * rs2;
    res.z = (o2 - mo) * rs2; res.w = (o3 - mo) * rs2;
    ((float4*)(out + (size_t)bs * DM))[lane] = res;
    if (lane == 0) out[(size_t)BB * SS * DM + bs] = 1.0f;  // att_mask
}

extern "C" void kernel_launch(void* const* d_in, const int* in_sizes, int n_in,
                              void* d_out, int out_size, void* d_ws, size_t ws_size,
                              hipStream_t stream) {
    const float* x     = (const float*)d_in[0];
    const float* vocab = (const float*)d_in[1];
    const float* wemb  = (const float*)d_in[2];
    const float* hemb  = (const float*)d_in[3];
    float* out = (float*)d_out;

    char* ws = (char*)d_ws;
    float* segn                  = (float*)ws;                              // 1 MB
    unsigned long long* bestkey  = (unsigned long long*)(ws + 1048576);     // 64 KB
    unsigned char* bucketc       = (unsigned char*)(ws + 1048576 + 65536);  // 8 KB
    float* hco                   = (float*)(ws + 1048576 + 65536 + 8192);   // 8 KB
    float* pe_g                  = (float*)(ws + 1048576 + 65536 + 16384);  // 256 KB
    int* bucket_cnt              = (int*)(ws + 1048576 + 65536 + 16384 + 262144);   // 1 KB
    int* list_g                  = (int*)(ws + 1048576 + 65536 + 16384 + 262144 + 1024); // 2 MB

    hipMemsetAsync(bucket_cnt, 0, 256 * sizeof(int), stream);
    prep_haar_pe_kernel<<<1312, 256, 0, stream>>>(x, segn, bucketc, bestkey,
                                                  hco, pe_g, bucket_cnt, list_g);
    search_kernel<<<256 * SPLIT, 512, 0, stream>>>(vocab, segn, bucket_cnt,
                                                   list_g, bestkey);
    out_kernel<<<2048, 256, 0, stream>>>(wemb, hemb, hco, pe_g, bucketc,
                                         bestkey, out);
}